// Round 7
// baseline (372.664 us; speedup 1.0000x reference)
//
#include <hip/hip_runtime.h>
#include <hip/hip_bf16.h>

#define IN_F  4096
#define OUT_F 4096
#define NTOK  4096
#define RANK  32
#define GS    64
#define NG    64
#define KTOT  4224          // 4096 + 32 (low-rank) + 96 zero pad -> 66 * 64
#define NKT   66
#define ITERS 33
#define KCH   1024

typedef __attribute__((ext_vector_type(4))) float f32x4;
typedef __attribute__((ext_vector_type(8))) short bf16x8;

__device__ __forceinline__ ushort f2bf(float f) {
  union { float f; uint u; } c; c.f = f;
  const uint u = c.u;
  return (ushort)((u + 0x7fffu + ((u >> 16) & 1u)) >> 16);  // RNE
}

// ---------------------------------------------------------------------------
// Kernel 1: per-group int8 quant + dequant of x -> A_ext[:, 0:4096] (bf16)
// ---------------------------------------------------------------------------
__global__ __launch_bounds__(256)
void quant_kernel(const float* __restrict__ x, ushort* __restrict__ Aext)
{
  const int tid  = threadIdx.x;
  const int wave = tid >> 6, lane = tid & 63;
  const int sub  = lane & 15;
  const int ggrp = blockIdx.x * 16 + wave * 4 + (lane >> 4);
  const int row  = ggrp >> 6, g = ggrp & 63;

  const float4 v = *(const float4*)(x + (size_t)row * IN_F + g * GS + sub * 4);
  float m = fmaxf(fmaxf(fabsf(v.x), fabsf(v.y)), fmaxf(fabsf(v.z), fabsf(v.w)));
  m = fmaxf(m, __shfl_xor(m, 1));
  m = fmaxf(m, __shfl_xor(m, 2));
  m = fmaxf(m, __shfl_xor(m, 4));
  m = fmaxf(m, __shfl_xor(m, 8));
  const float ascale = (m > 0.f) ? m * (1.f / 127.f) : 1.f;

  const float d0 = fminf(fmaxf(rintf(v.x / ascale), -127.f), 127.f) * ascale;
  const float d1 = fminf(fmaxf(rintf(v.y / ascale), -127.f), 127.f) * ascale;
  const float d2 = fminf(fmaxf(rintf(v.z / ascale), -127.f), 127.f) * ascale;
  const float d3 = fminf(fmaxf(rintf(v.w / ascale), -127.f), 127.f) * ascale;

  uint2 st;
  st.x = (uint)f2bf(d0) | ((uint)f2bf(d1) << 16);
  st.y = (uint)f2bf(d2) | ((uint)f2bf(d3) << 16);
  *(uint2*)(Aext + (size_t)row * KTOT + g * GS + sub * 4) = st;
}

// ---------------------------------------------------------------------------
// Kernel 2: dequant int4 weights -> B_ext[:, 0:4096] (bf16)
// ---------------------------------------------------------------------------
__global__ __launch_bounds__(256)
void wdeq_kernel(const int* __restrict__ qw, const float* __restrict__ wsc,
                 ushort* __restrict__ Bext)
{
  const int gidx = blockIdx.x * 256 + threadIdx.x;
  const int o  = gidx >> 9;
  const int i0 = (gidx & 511) << 3;
  const float sc = wsc[o * NG + (i0 >> 6)];
  const int4 qa = *(const int4*)(qw + (size_t)o * IN_F + i0);
  const int4 qb = *(const int4*)(qw + (size_t)o * IN_F + i0 + 4);
  uint4 st;
  st.x = (uint)f2bf(qa.x * sc) | ((uint)f2bf(qa.y * sc) << 16);
  st.y = (uint)f2bf(qa.z * sc) | ((uint)f2bf(qa.w * sc) << 16);
  st.z = (uint)f2bf(qb.x * sc) | ((uint)f2bf(qb.y * sc) << 16);
  st.w = (uint)f2bf(qb.z * sc) | ((uint)f2bf(qb.w * sc) << 16);
  *(uint4*)(Bext + (size_t)o * KTOT + i0) = st;
}

// ---------------------------------------------------------------------------
// Kernel 3 (aux): pu^T -> B_ext[:, 4096:4128] + zero pad 4128:4224; pd -> pdT.
// ---------------------------------------------------------------------------
__global__ __launch_bounds__(256)
void aux_kernel(const float* __restrict__ pd, const float* __restrict__ pu,
                ushort* __restrict__ Bext, ushort* __restrict__ pdT)
{
  const int id = blockIdx.x * 256 + threadIdx.x;   // 0..4095
  ushort* dst = Bext + (size_t)id * KTOT + IN_F;
  #pragma unroll
  for (int r = 0; r < RANK; ++r) {
    dst[r]            = f2bf(pu[(size_t)r * OUT_F + id]);
    dst[RANK + r]     = 0;
    dst[2 * RANK + r] = 0;
    dst[3 * RANK + r] = 0;
  }
  #pragma unroll
  for (int r = 0; r < RANK; ++r)
    pdT[(size_t)r * IN_F + id] = f2bf(pd[(size_t)id * RANK + r]);
}

// ---------------------------------------------------------------------------
// Kernel 4: lr partials = Aq @ pdT^T via MFMA (64 M-tiles x 4 K-chunks).
// ---------------------------------------------------------------------------
__global__ __launch_bounds__(256)
void lr_kernel(const ushort* __restrict__ A, const ushort* __restrict__ pdT,
               float* __restrict__ part)
{
  __shared__ alignas(16) ushort lA[64 * 64];
  const int tid  = threadIdx.x;
  const int wave = tid >> 6, lane = tid & 63;
  const int mt = blockIdx.x >> 2;
  const int kc = blockIdx.x & 3;
  const int k0 = kc * KCH;

  const int tr  = tid >> 3;
  const int scc = (tid & 7) ^ (tr & 7);
  const ushort* aSrc = A + (size_t)(mt * 64 + tr) * KTOT + k0 + scc * 8;
  char* ldsA = (char*)lA + wave * 1024;

  f32x4 acc[2];
  #pragma unroll
  for (int n = 0; n < 2; ++n) acc[n] = f32x4{0.f, 0.f, 0.f, 0.f};

  for (int kt = 0; kt < KCH / 64; ++kt) {
    const ushort* aS = aSrc + kt * 64;
    #pragma unroll
    for (int j = 0; j < 2; ++j)
      __builtin_amdgcn_global_load_lds(
          (const __attribute__((address_space(1))) void*)(aS + (size_t)j * 32 * KTOT),
          (__attribute__((address_space(3))) void*)(ldsA + j * 4096), 16, 0, 0);
    __syncthreads();
    #pragma unroll
    for (int ks = 0; ks < 2; ++ks) {
      const int kb  = (ks * 32 + (lane >> 4) * 8) * 2;
      const int row = wave * 16 + (lane & 15);
      const int addr = (row * 128 + kb) ^ ((row & 7) << 4);
      bf16x8 af = *(const bf16x8*)((const char*)lA + addr);
      #pragma unroll
      for (int n = 0; n < 2; ++n) {
        const int prow = n * 16 + (lane & 15);
        bf16x8 bf = *(const bf16x8*)(pdT + (size_t)prow * IN_F + k0 + kt * 64 + ks * 32 + (lane >> 4) * 8);
        acc[n] = __builtin_amdgcn_mfma_f32_16x16x32_bf16(af, bf, acc[n], 0, 0, 0);
      }
    }
    __syncthreads();
  }
  const int r0   = lane & 15;
  const int rowb = mt * 64 + wave * 16 + (lane >> 4) * 4;
  #pragma unroll
  for (int n = 0; n < 2; ++n)
    #pragma unroll
    for (int i = 0; i < 4; ++i)
      part[((size_t)kc * 4096 + rowb + i) * 32 + n * 16 + r0] = acc[n][i];
}

// ---------------------------------------------------------------------------
// Kernel 5: combine lr partials -> A_ext[:, 4096:4128], zero 4128:4224.
// ---------------------------------------------------------------------------
__global__ __launch_bounds__(256)
void lrcomb_kernel(const float* __restrict__ part, ushort* __restrict__ Aext)
{
  const int id  = blockIdx.x * 256 + threadIdx.x;
  const int row = id >> 5, r = id & 31;
  const float s = part[(size_t)row * 32 + r]
                + part[(size_t)(4096 + row) * 32 + r]
                + part[(size_t)(8192 + row) * 32 + r]
                + part[(size_t)(12288 + row) * 32 + r];
  ushort* dst = Aext + (size_t)row * KTOT + IN_F;
  dst[r]            = f2bf(s);
  dst[RANK + r]     = 0;
  dst[2 * RANK + r] = 0;
  dst[3 * RANK + r] = 0;
}

// ---------------------------------------------------------------------------
// Kernel 6: 256x256 8-phase GEMM, R7: one-phase READ-AHEAD register pipeline.
// LDS: A buf b at b*32768 (quarter q of 64 rows at +q*8192),
//      B at 65536 + b*32768.  XOR swizzle ((r&7)<<4).
// Phase p: [STAGE][drain@4,8][BAR][reads for p+1][MFMA p (setprio)][BAR].
// Frag sets: afX/afY (A double-buf), b0X/b0Y (B-NQ0, held 4 phases), b1
// (B-NQ1, 2-phase life, single buffer). Reads/phase: 4,8,0,12,4,8,0,12.
// vmcnt(4) drains BEFORE the barrier at phases 4/8; ledger verified:
// every read's source stage completes above the nearest drain-wall.
// Tail stages clamped to tile 65 (zeros) -> iteration-invariant vmcnt queue.
// ---------------------------------------------------------------------------
__device__ __forceinline__ void stageA(const ushort* __restrict__ Atile, char* lds,
                                       int b, int h, int kt, int w, int lane)
{
  #pragma unroll
  for (int l = 0; l < 2; ++l) {
    const int g = w * 2 + l;
    const int quarter = h + (g >> 3) * 2;
    const int sub = g & 7;
    const int grow = quarter * 64 + sub * 8 + (lane >> 3);
    const ushort* src = Atile + (size_t)grow * KTOT + kt * 64 + (((lane & 7) ^ (lane >> 3)) << 3);
    __builtin_amdgcn_global_load_lds(
        (const __attribute__((address_space(1))) void*)src,
        (__attribute__((address_space(3))) void*)(lds + b * 32768 + quarter * 8192 + sub * 1024),
        16, 0, 0);
  }
}

__device__ __forceinline__ void stageB(const ushort* __restrict__ Btile, char* lds,
                                       int b, int h, int kt, int w, int lane)
{
  #pragma unroll
  for (int l = 0; l < 2; ++l) {
    const int g = w * 2 + l;
    const int j = g >> 2;
    const int sub = g & 3;
    const int grow = j * 64 + h * 32 + sub * 8 + (lane >> 3);
    const ushort* src = Btile + (size_t)grow * KTOT + kt * 64 + (((lane & 7) ^ (lane >> 3)) << 3);
    __builtin_amdgcn_global_load_lds(
        (const __attribute__((address_space(1))) void*)src,
        (__attribute__((address_space(3))) void*)(lds + 65536 + b * 32768 + j * 8192 + h * 4096 + sub * 1024),
        16, 0, 0);
  }
}

#define READ_AF(DST, B_, MQ_)                                                    \
  {                                                                              \
    const int aqb = (B_) * 32768 + (wm * 2 + (MQ_)) * 8192;                      \
    _Pragma("unroll")                                                            \
    for (int mf = 0; mf < 4; ++mf) {                                             \
      const int r = mf * 16 + l15;                                               \
      _Pragma("unroll")                                                          \
      for (int ks = 0; ks < 2; ++ks)                                             \
        DST[mf][ks] = *(const bf16x8*)(lds + aqb +                               \
            (((r * 128) + kbyte[ks]) ^ ((r & 7) << 4)));                         \
    }                                                                            \
  }

#define READ_BF(DST, B_, NQ_)                                                    \
  {                                                                              \
    const int bqb = 65536 + (B_) * 32768 + wn * 8192;                            \
    _Pragma("unroll")                                                            \
    for (int nf = 0; nf < 2; ++nf) {                                             \
      const int r = ((NQ_) * 2 + nf) * 16 + l15;                                 \
      _Pragma("unroll")                                                          \
      for (int ks = 0; ks < 2; ++ks)                                             \
        DST[nf][ks] = *(const bf16x8*)(lds + bqb +                               \
            (((r * 128) + kbyte[ks]) ^ ((r & 7) << 4)));                         \
    }                                                                            \
  }

#define MFMA16(MQ_, NQ_, AF, BF)                                                 \
  __builtin_amdgcn_s_setprio(1);                                                 \
  _Pragma("unroll")                                                              \
  for (int mf = 0; mf < 4; ++mf)                                                 \
    _Pragma("unroll")                                                            \
    for (int nf = 0; nf < 2; ++nf)                                               \
      _Pragma("unroll")                                                          \
      for (int ks = 0; ks < 2; ++ks)                                             \
        acc[(MQ_) * 4 + mf][(NQ_) * 2 + nf] =                                    \
            __builtin_amdgcn_mfma_f32_16x16x32_bf16(AF[mf][ks], BF[nf][ks],      \
                acc[(MQ_) * 4 + mf][(NQ_) * 2 + nf], 0, 0, 0);                   \
  __builtin_amdgcn_s_setprio(0);

#define BAR __builtin_amdgcn_s_barrier()
#define DRAIN4 asm volatile("s_waitcnt vmcnt(4)" ::: "memory")

__global__ __launch_bounds__(512, 2)
void gemm256_kernel(const ushort* __restrict__ A, const ushort* __restrict__ B,
                    const float* __restrict__ bias, float* __restrict__ C)
{
  extern __shared__ char lds[];
  const int tid = threadIdx.x;
  const int w = tid >> 6, lane = tid & 63;
  const int l15 = lane & 15;
  const int wm = w >> 2, wn = w & 3;          // 2 x 4 waves
  int kbyte[2];
  kbyte[0] = ((lane >> 4) * 8) * 2;
  kbyte[1] = (32 + (lane >> 4) * 8) * 2;

  // 2-D XCD chunk swizzle: each XCD owns a 4x8 (bm x bn) region.
  const int xcd = blockIdx.x & 7, idx = blockIdx.x >> 3;
  const int bm = (xcd >> 1) * 4 + (idx >> 3);
  const int bn = (xcd & 1) * 8 + (idx & 7);

  const ushort* Atile = A + (size_t)bm * 256 * KTOT;
  const ushort* Btile = B + (size_t)bn * 256 * KTOT;

  f32x4 acc[8][4];
  #pragma unroll
  for (int m = 0; m < 8; ++m)
    #pragma unroll
    for (int n = 0; n < 4; ++n)
      acc[m][n] = f32x4{0.f, 0.f, 0.f, 0.f};

  bf16x8 afX[4][2], afY[4][2], b0X[2][2], b0Y[2][2], b1[2][2];

  // Prologue: buf0 <- tile 0 (all 4 halves), buf1 <- tile 1 (A_H0, B_H0).
  stageA(Atile, lds, 0, 0, 0, w, lane);
  stageB(Btile, lds, 0, 0, 0, w, lane);
  stageB(Btile, lds, 0, 1, 0, w, lane);
  stageA(Atile, lds, 0, 1, 0, w, lane);
  stageA(Atile, lds, 1, 0, 1, w, lane);
  stageB(Btile, lds, 1, 0, 1, w, lane);
  DRAIN4;                      // tile-0 stages complete; carry = 2 t1 stages
  BAR;
  READ_AF(afX, 0, 0);          // frags for phase 1
  READ_BF(b0X, 0, 0);

  #pragma unroll 1
  for (int j = 0; j < ITERS; ++j) {
    const int t1 = 2 * j + 1;
    const int t2 = (2 * j + 2 < NKT) ? 2 * j + 2 : NKT - 1;   // clamped
    const int t3 = (2 * j + 3 < NKT) ? 2 * j + 3 : NKT - 1;   // (tile 65 = 0)

    // ph1: compute (0,0) buf0; read b1 <- B(0,NQ1)
    stageB(Btile, lds, 1, 1, t1, w, lane);
    BAR;
    READ_BF(b1, 0, 1);
    MFMA16(0, 0, afX, b0X);
    BAR;
    // ph2: compute (0,1) buf0; read afY <- A(0,MQ1)
    stageA(Atile, lds, 1, 1, t1, w, lane);
    BAR;
    READ_AF(afY, 0, 1);
    MFMA16(0, 1, afX, b1);
    BAR;
    // ph3: compute (1,1) buf0; no reads
    stageA(Atile, lds, 0, 0, t2, w, lane);
    BAR;
    MFMA16(1, 1, afY, b1);
    BAR;
    // ph4: compute (1,0) buf0; drain; read afX <- A(1,MQ0), b0Y <- B(1,NQ0)
    stageB(Btile, lds, 0, 0, t2, w, lane);
    DRAIN4;
    BAR;
    READ_AF(afX, 1, 0);
    READ_BF(b0Y, 1, 0);
    MFMA16(1, 0, afY, b0X);
    BAR;
    // ph5: compute (0,0) buf1; read b1 <- B(1,NQ1)
    stageB(Btile, lds, 0, 1, t2, w, lane);
    BAR;
    READ_BF(b1, 1, 1);
    MFMA16(0, 0, afX, b0Y);
    BAR;
    // ph6: compute (0,1) buf1; read afY <- A(1,MQ1)
    stageA(Atile, lds, 0, 1, t2, w, lane);
    BAR;
    READ_AF(afY, 1, 1);
    MFMA16(0, 1, afX, b1);
    BAR;
    // ph7: compute (1,1) buf1; no reads
    stageA(Atile, lds, 1, 0, t3, w, lane);
    BAR;
    MFMA16(1, 1, afY, b1);
    BAR;
    // ph8: compute (1,0) buf1; drain; read afX <- A(0,MQ0), b0X <- B(0,NQ0)
    stageB(Btile, lds, 1, 0, t3, w, lane);
    DRAIN4;
    BAR;
    READ_AF(afX, 0, 0);
    READ_BF(b0X, 0, 0);
    MFMA16(1, 0, afY, b0Y);
    BAR;
  }

  // Epilogue: C = acc + bias. acc frag: col = l15, row = (lane>>4)*4 + i.
  const int csub = lane >> 4;
  #pragma unroll
  for (int nf = 0; nf < 4; ++nf) {
    const int col = bn * 256 + wn * 64 + nf * 16 + l15;
    const float bv = bias[col];
    #pragma unroll
    for (int mf = 0; mf < 8; ++mf) {
      const int row = bm * 256 + wm * 128 + mf * 16 + csub * 4;
      #pragma unroll
      for (int i = 0; i < 4; ++i)
        C[(size_t)(row + i) * OUT_F + col] = acc[mf][nf][i] + bv;
    }
  }
}

// ---------------------------------------------------------------------------
extern "C" void kernel_launch(void* const* d_in, const int* in_sizes, int n_in,
                              void* d_out, int out_size, void* d_ws, size_t ws_size,
                              hipStream_t stream) {
  const float* x    = (const float*)d_in[0];
  const int*   qw   = (const int*)d_in[1];
  const float* wsc  = (const float*)d_in[2];
  const float* bias = (const float*)d_in[3];
  const float* pd   = (const float*)d_in[4];
  const float* pu   = (const float*)d_in[5];
  float* out = (float*)d_out;

  ushort* Aext = (ushort*)d_ws;                        // [4096][4224] bf16
  ushort* Bext = Aext + (size_t)NTOK * KTOT;           // [4096][4224] bf16
  ushort* pdT  = Bext + (size_t)OUT_F * KTOT;          // [32][4096] bf16
  float*  part = (float*)(pdT + (size_t)RANK * IN_F);  // [4][4096][32] f32

  hipFuncSetAttribute(reinterpret_cast<const void*>(gemm256_kernel),
                      hipFuncAttributeMaxDynamicSharedMemorySize, 131072);

  quant_kernel <<<16384, 256, 0, stream>>>(x, Aext);
  wdeq_kernel  <<< 8192, 256, 0, stream>>>(qw, wsc, Bext);
  aux_kernel   <<<   16, 256, 0, stream>>>(pd, pu, Bext, pdT);
  lr_kernel    <<<  256, 256, 0, stream>>>(Aext, pdT, part);
  lrcomb_kernel<<<  512, 256, 0, stream>>>(part, Aext);
  gemm256_kernel<<< 256, 512, 131072, stream>>>(Aext, Bext, bias, out);
}

// Round 9
// 224.723 us; speedup vs baseline: 1.6583x; 1.6583x over previous
//
#include <hip/hip_runtime.h>
#include <hip/hip_bf16.h>

#define IN_F  4096
#define OUT_F 4096
#define NTOK  4096
#define RANK  32
#define GS    64
#define NG    64
#define KTOT  4224          // 4096 + 32 (low-rank) + 96 zero pad -> 66 * 64
#define NKT   66
#define ITERS 33
#define KCH   1024

typedef __attribute__((ext_vector_type(4))) float f32x4;
typedef __attribute__((ext_vector_type(8))) short bf16x8;

#define AS1 __attribute__((address_space(1)))
#define AS3 __attribute__((address_space(3)))

__device__ __forceinline__ ushort f2bf(float f) {
  union { float f; uint u; } c; c.f = f;
  const uint u = c.u;
  return (ushort)((u + 0x7fffu + ((u >> 16) & 1u)) >> 16);  // RNE
}

// ---------------------------------------------------------------------------
// Kernel 1: per-group int8 quant + dequant of x -> A_ext[:, 0:4096] (bf16)
// ---------------------------------------------------------------------------
__global__ __launch_bounds__(256)
void quant_kernel(const float* __restrict__ x, ushort* __restrict__ Aext)
{
  const int tid  = threadIdx.x;
  const int wave = tid >> 6, lane = tid & 63;
  const int sub  = lane & 15;
  const int ggrp = blockIdx.x * 16 + wave * 4 + (lane >> 4);
  const int row  = ggrp >> 6, g = ggrp & 63;

  const float4 v = *(const float4*)(x + (size_t)row * IN_F + g * GS + sub * 4);
  float m = fmaxf(fmaxf(fabsf(v.x), fabsf(v.y)), fmaxf(fabsf(v.z), fabsf(v.w)));
  m = fmaxf(m, __shfl_xor(m, 1));
  m = fmaxf(m, __shfl_xor(m, 2));
  m = fmaxf(m, __shfl_xor(m, 4));
  m = fmaxf(m, __shfl_xor(m, 8));
  const float ascale = (m > 0.f) ? m * (1.f / 127.f) : 1.f;

  const float d0 = fminf(fmaxf(rintf(v.x / ascale), -127.f), 127.f) * ascale;
  const float d1 = fminf(fmaxf(rintf(v.y / ascale), -127.f), 127.f) * ascale;
  const float d2 = fminf(fmaxf(rintf(v.z / ascale), -127.f), 127.f) * ascale;
  const float d3 = fminf(fmaxf(rintf(v.w / ascale), -127.f), 127.f) * ascale;

  uint2 st;
  st.x = (uint)f2bf(d0) | ((uint)f2bf(d1) << 16);
  st.y = (uint)f2bf(d2) | ((uint)f2bf(d3) << 16);
  *(uint2*)(Aext + (size_t)row * KTOT + g * GS + sub * 4) = st;
}

// ---------------------------------------------------------------------------
// Kernel 2: dequant int4 weights -> B_ext[:, 0:4096] (bf16)
// ---------------------------------------------------------------------------
__global__ __launch_bounds__(256)
void wdeq_kernel(const int* __restrict__ qw, const float* __restrict__ wsc,
                 ushort* __restrict__ Bext)
{
  const int gidx = blockIdx.x * 256 + threadIdx.x;
  const int o  = gidx >> 9;
  const int i0 = (gidx & 511) << 3;
  const float sc = wsc[o * NG + (i0 >> 6)];
  const int4 qa = *(const int4*)(qw + (size_t)o * IN_F + i0);
  const int4 qb = *(const int4*)(qw + (size_t)o * IN_F + i0 + 4);
  uint4 st;
  st.x = (uint)f2bf(qa.x * sc) | ((uint)f2bf(qa.y * sc) << 16);
  st.y = (uint)f2bf(qa.z * sc) | ((uint)f2bf(qa.w * sc) << 16);
  st.z = (uint)f2bf(qb.x * sc) | ((uint)f2bf(qb.y * sc) << 16);
  st.w = (uint)f2bf(qb.z * sc) | ((uint)f2bf(qb.w * sc) << 16);
  *(uint4*)(Bext + (size_t)o * KTOT + i0) = st;
}

// ---------------------------------------------------------------------------
// Kernel 3 (aux): pu^T -> B_ext[:, 4096:4128] + zero pad 4128:4224; pd -> pdT.
// ---------------------------------------------------------------------------
__global__ __launch_bounds__(256)
void aux_kernel(const float* __restrict__ pd, const float* __restrict__ pu,
                ushort* __restrict__ Bext, ushort* __restrict__ pdT)
{
  const int id = blockIdx.x * 256 + threadIdx.x;   // 0..4095
  ushort* dst = Bext + (size_t)id * KTOT + IN_F;
  #pragma unroll
  for (int r = 0; r < RANK; ++r) {
    dst[r]            = f2bf(pu[(size_t)r * OUT_F + id]);
    dst[RANK + r]     = 0;
    dst[2 * RANK + r] = 0;
    dst[3 * RANK + r] = 0;
  }
  #pragma unroll
  for (int r = 0; r < RANK; ++r)
    pdT[(size_t)r * IN_F + id] = f2bf(pd[(size_t)id * RANK + r]);
}

// ---------------------------------------------------------------------------
// Kernel 4: lr partials = Aq @ pdT^T via MFMA (64 M-tiles x 4 K-chunks).
// ---------------------------------------------------------------------------
__global__ __launch_bounds__(256)
void lr_kernel(const ushort* __restrict__ A, const ushort* __restrict__ pdT,
               float* __restrict__ part)
{
  __shared__ alignas(16) ushort lA[64 * 64];
  const int tid  = threadIdx.x;
  const int wave = tid >> 6, lane = tid & 63;
  const int mt = blockIdx.x >> 2;
  const int kc = blockIdx.x & 3;
  const int k0 = kc * KCH;

  const int tr  = tid >> 3;
  const int scc = (tid & 7) ^ (tr & 7);
  const ushort* aSrc = A + (size_t)(mt * 64 + tr) * KTOT + k0 + scc * 8;
  char* ldsA = (char*)lA + wave * 1024;

  f32x4 acc[2];
  #pragma unroll
  for (int n = 0; n < 2; ++n) acc[n] = f32x4{0.f, 0.f, 0.f, 0.f};

  for (int kt = 0; kt < KCH / 64; ++kt) {
    const ushort* aS = aSrc + kt * 64;
    #pragma unroll
    for (int j = 0; j < 2; ++j)
      __builtin_amdgcn_global_load_lds(
          (const AS1 void*)(aS + (size_t)j * 32 * KTOT),
          (AS3 void*)(ldsA + j * 4096), 16, 0, 0);
    __syncthreads();
    #pragma unroll
    for (int ks = 0; ks < 2; ++ks) {
      const int kb  = (ks * 32 + (lane >> 4) * 8) * 2;
      const int row = wave * 16 + (lane & 15);
      const int addr = (row * 128 + kb) ^ ((row & 7) << 4);
      bf16x8 af = *(const bf16x8*)((const char*)lA + addr);
      #pragma unroll
      for (int n = 0; n < 2; ++n) {
        const int prow = n * 16 + (lane & 15);
        bf16x8 bf = *(const bf16x8*)(pdT + (size_t)prow * IN_F + k0 + kt * 64 + ks * 32 + (lane >> 4) * 8);
        acc[n] = __builtin_amdgcn_mfma_f32_16x16x32_bf16(af, bf, acc[n], 0, 0, 0);
      }
    }
    __syncthreads();
  }
  const int r0   = lane & 15;
  const int rowb = mt * 64 + wave * 16 + (lane >> 4) * 4;
  #pragma unroll
  for (int n = 0; n < 2; ++n)
    #pragma unroll
    for (int i = 0; i < 4; ++i)
      part[((size_t)kc * 4096 + rowb + i) * 32 + n * 16 + r0] = acc[n][i];
}

// ---------------------------------------------------------------------------
// Kernel 5: combine lr partials -> A_ext[:, 4096:4128], zero 4128:4224.
// ---------------------------------------------------------------------------
__global__ __launch_bounds__(256)
void lrcomb_kernel(const float* __restrict__ part, ushort* __restrict__ Aext)
{
  const int id  = blockIdx.x * 256 + threadIdx.x;
  const int row = id >> 5, r = id & 31;
  const float s = part[(size_t)row * 32 + r]
                + part[(size_t)(4096 + row) * 32 + r]
                + part[(size_t)(8192 + row) * 32 + r]
                + part[(size_t)(12288 + row) * 32 + r];
  ushort* dst = Aext + (size_t)row * KTOT + IN_F;
  dst[r]            = f2bf(s);
  dst[RANK + r]     = 0;
  dst[2 * RANK + r] = 0;
  dst[3 * RANK + r] = 0;
}

// ---------------------------------------------------------------------------
// Kernel 6: 256x256 GEMM, R8: one-phase-ahead reads, 4 frag sets (96 regs),
// quadrant order (0,0),(1,0),(0,1),(1,1). One barrier/phase; vmcnt(4) at
// even-phase ends (drains stages issued 2 phases earlier). LDS: A [0,64K)
// (buf b at b*32768, quarter q at +q*8192), B [64K,128K). Swizzle ^((r&7)<<4).
// ds_read addressing: 4 base VGPRs + compile-time immediates (fit 16-bit;
// B base folds +65536 into the VGPR so imm <= 38912).
// Ledger (stage -> first read, all >= 2-phase gap, guarded by even drains):
//  p1 stA(1,h1,t1)->p5 | p2 stB(1,h1,t1)->p6 | p3 stA(0,h0,t2)->p7t
//  p4 stB(0,h0,t2)->p8 | p5 stA(0,h1,t2)->p1' | p6 stB(0,h1,t2)->p2'
//  p7 stA(1,h0,t3)->p3't | p8 stB(1,h0,t3)->p4'
// ---------------------------------------------------------------------------
#define READ_AF8(DST, B_, MQ_)                                                   \
  { _Pragma("unroll")                                                            \
    for (int mf = 0; mf < 4; ++mf) {                                             \
      DST[mf][0] = *(const bf16x8*)(lds + afB0 + ((B_) * 32768 + (MQ_) * 8192 + mf * 2048)); \
      DST[mf][1] = *(const bf16x8*)(lds + afB1 + ((B_) * 32768 + (MQ_) * 8192 + mf * 2048)); \
    } }

#define READ_AF_H(DST, B_, MQ_, MF0)                                             \
  { _Pragma("unroll")                                                            \
    for (int mf = (MF0); mf < (MF0) + 2; ++mf) {                                 \
      DST[mf][0] = *(const bf16x8*)(lds + afB0 + ((B_) * 32768 + (MQ_) * 8192 + mf * 2048)); \
      DST[mf][1] = *(const bf16x8*)(lds + afB1 + ((B_) * 32768 + (MQ_) * 8192 + mf * 2048)); \
    } }

#define READ_BF4(DST, B_, NQ_)                                                   \
  { _Pragma("unroll")                                                            \
    for (int nf = 0; nf < 2; ++nf) {                                             \
      DST[nf][0] = *(const bf16x8*)(lds + bfB0 + ((B_) * 32768 + (NQ_) * 4096 + nf * 2048)); \
      DST[nf][1] = *(const bf16x8*)(lds + bfB1 + ((B_) * 32768 + (NQ_) * 4096 + nf * 2048)); \
    } }

#define MFMA16(MQ_, NQ_, AF, BF)                                                 \
  __builtin_amdgcn_s_setprio(1);                                                 \
  _Pragma("unroll")                                                              \
  for (int mf = 0; mf < 4; ++mf)                                                 \
    _Pragma("unroll")                                                            \
    for (int nf = 0; nf < 2; ++nf)                                               \
      _Pragma("unroll")                                                          \
      for (int ks = 0; ks < 2; ++ks)                                             \
        acc[(MQ_) * 4 + mf][(NQ_) * 2 + nf] =                                    \
            __builtin_amdgcn_mfma_f32_16x16x32_bf16(AF[mf][ks], BF[nf][ks],      \
                acc[(MQ_) * 4 + mf][(NQ_) * 2 + nf], 0, 0, 0);                   \
  __builtin_amdgcn_s_setprio(0);

#define STAGE_A(B_, S0, S1, D0, D1, T_)                                          \
  { const ushort* s0 = Atile + S0 + (T_) * 64;                                   \
    const ushort* s1 = Atile + S1 + (T_) * 64;                                   \
    __builtin_amdgcn_global_load_lds((const AS1 void*)s0,                        \
        (AS3 void*)(lds + (B_) * 32768 + D0), 16, 0, 0);                         \
    __builtin_amdgcn_global_load_lds((const AS1 void*)s1,                        \
        (AS3 void*)(lds + (B_) * 32768 + D1), 16, 0, 0); }

#define STAGE_B(B_, S0, S1, D0, D1, T_)                                          \
  { const ushort* s0 = Btile + S0 + (T_) * 64;                                   \
    const ushort* s1 = Btile + S1 + (T_) * 64;                                   \
    __builtin_amdgcn_global_load_lds((const AS1 void*)s0,                        \
        (AS3 void*)(lds + 65536 + (B_) * 32768 + D0), 16, 0, 0);                 \
    __builtin_amdgcn_global_load_lds((const AS1 void*)s1,                        \
        (AS3 void*)(lds + 65536 + (B_) * 32768 + D1), 16, 0, 0); }

#define BAR __builtin_amdgcn_s_barrier()
#define DRAIN4 asm volatile("s_waitcnt vmcnt(4)" ::: "memory")

__global__ __launch_bounds__(512, 2)
void gemm256_kernel(const ushort* __restrict__ A, const ushort* __restrict__ B,
                    const float* __restrict__ bias, float* __restrict__ C)
{
  extern __shared__ char lds[];
  const int tid = threadIdx.x;
  const int w = tid >> 6, lane = tid & 63;
  const int l15 = lane & 15;
  const int wm = w >> 2, wn = w & 3;          // 2 x 4 waves

  // ds_read base vaddrs (4 regs); imm offsets carry B_/MQ_/NQ_/frag.
  const int swz0 = (l15 * 128 + (lane >> 4) * 16) ^ ((l15 & 7) << 4);
  const int swz1 = (l15 * 128 + 64 + (lane >> 4) * 16) ^ ((l15 & 7) << 4);
  const int afB0 = wm * 16384 + swz0;
  const int afB1 = wm * 16384 + swz1;
  const int bfB0 = 65536 + wn * 8192 + swz0;
  const int bfB1 = 65536 + wn * 8192 + swz1;

  // Stage source offsets (ushort units) and LDS dest offsets (bytes).
  const int coff = ((lane & 7) ^ (lane >> 3)) << 3;
  const int g0 = w * 2, g1 = w * 2 + 1;
  const int aq0 = (g0 >> 3) * 2, asub0 = g0 & 7;
  const int aq1 = (g1 >> 3) * 2, asub1 = g1 & 7;
  const int aS00 = (aq0 * 64 + asub0 * 8 + (lane >> 3)) * KTOT + coff;           // h=0,l=0
  const int aS01 = (aq1 * 64 + asub1 * 8 + (lane >> 3)) * KTOT + coff;           // h=0,l=1
  const int aS10 = ((aq0 + 1) * 64 + asub0 * 8 + (lane >> 3)) * KTOT + coff;     // h=1,l=0
  const int aS11 = ((aq1 + 1) * 64 + asub1 * 8 + (lane >> 3)) * KTOT + coff;     // h=1,l=1
  const int aD00 = aq0 * 8192 + asub0 * 1024;
  const int aD01 = aq1 * 8192 + asub1 * 1024;
  const int aD10 = (aq0 + 1) * 8192 + asub0 * 1024;
  const int aD11 = (aq1 + 1) * 8192 + asub1 * 1024;
  const int bj0 = g0 >> 2, bsub0 = g0 & 3;
  const int bj1 = g1 >> 2, bsub1 = g1 & 3;
  const int bS00 = (bj0 * 64 + bsub0 * 8 + (lane >> 3)) * KTOT + coff;
  const int bS01 = (bj1 * 64 + bsub1 * 8 + (lane >> 3)) * KTOT + coff;
  const int bS10 = (bj0 * 64 + 32 + bsub0 * 8 + (lane >> 3)) * KTOT + coff;
  const int bS11 = (bj1 * 64 + 32 + bsub1 * 8 + (lane >> 3)) * KTOT + coff;
  const int bD00 = bj0 * 8192 + bsub0 * 1024;
  const int bD01 = bj1 * 8192 + bsub1 * 1024;
  const int bD10 = bj0 * 8192 + 4096 + bsub0 * 1024;
  const int bD11 = bj1 * 8192 + 4096 + bsub1 * 1024;

  // 2-D XCD chunk swizzle: each XCD owns a 4x8 (bm x bn) region.
  const int xcd = blockIdx.x & 7, idx = blockIdx.x >> 3;
  const int bm = (xcd >> 1) * 4 + (idx >> 3);
  const int bn = (xcd & 1) * 8 + (idx & 7);

  const ushort* Atile = A + (size_t)bm * 256 * KTOT;
  const ushort* Btile = B + (size_t)bn * 256 * KTOT;

  f32x4 acc[8][4];
  #pragma unroll
  for (int m = 0; m < 8; ++m)
    #pragma unroll
    for (int n = 0; n < 4; ++n)
      acc[m][n] = f32x4{0.f, 0.f, 0.f, 0.f};

  bf16x8 afA[4][2], afB[4][2], bA[2][2], bB[2][2];

  // Prologue: buf0 t0 full; buf1 t1 h0 halves. Leaves queue = 4 loads.
  STAGE_A(0, aS00, aS01, aD00, aD01, 0);   // A(0,h0,0)
  STAGE_B(0, bS00, bS01, bD00, bD01, 0);   // B(0,h0,0)
  STAGE_A(0, aS10, aS11, aD10, aD11, 0);   // A(0,h1,0)
  STAGE_B(0, bS10, bS11, bD10, bD11, 0);   // B(0,h1,0)
  STAGE_A(1, aS00, aS01, aD00, aD01, 1);   // A(1,h0,1)
  STAGE_B(1, bS00, bS01, bD00, bD01, 1);   // B(1,h0,1)
  DRAIN4;
  BAR;
  READ_AF8(afA, 0, 0);
  READ_BF4(bA, 0, 0);

  #pragma unroll 1
  for (int j = 0; j < ITERS; ++j) {
    const int t1 = 2 * j + 1;
    const int t2 = (2 * j + 2 < NKT) ? 2 * j + 2 : NKT - 1;   // clamped
    const int t3 = (2 * j + 3 < NKT) ? 2 * j + 3 : NKT - 1;   // (tile 65 = 0)

    // p1: MFMA (0,0) buf0; read afB <- A(0,MQ1); stage A(1,h1,t1)
    READ_AF8(afB, 0, 1);
    STAGE_A(1, aS10, aS11, aD10, aD11, t1);
    MFMA16(0, 0, afA, bA);
    BAR;
    // p2: MFMA (1,0) buf0; read bB <- B(0,NQ1); stage B(1,h1,t1); drain
    READ_BF4(bB, 0, 1);
    STAGE_B(1, bS10, bS11, bD10, bD11, t1);
    MFMA16(1, 0, afB, bA);
    DRAIN4;
    BAR;
    // p3: MFMA (0,1) buf0; tail-read afA[0:2] <- A(1,MQ0); stage A(0,h0,t2)
    STAGE_A(0, aS00, aS01, aD00, aD01, t2);
    MFMA16(0, 1, afA, bB);
    READ_AF_H(afA, 1, 0, 0);
    BAR;
    // p4: MFMA (1,1) buf0; read afA[2:4], bA <- buf1 NQ0; stage B(0,h0,t2); drain
    READ_AF_H(afA, 1, 0, 2);
    READ_BF4(bA, 1, 0);
    STAGE_B(0, bS00, bS01, bD00, bD01, t2);
    MFMA16(1, 1, afB, bB);
    DRAIN4;
    BAR;
    // p5: MFMA (0,0) buf1; read afB <- A(1,MQ1); stage A(0,h1,t2)
    READ_AF8(afB, 1, 1);
    STAGE_A(0, aS10, aS11, aD10, aD11, t2);
    MFMA16(0, 0, afA, bA);
    BAR;
    // p6: MFMA (1,0) buf1; read bB <- B(1,NQ1); stage B(0,h1,t2); drain
    READ_BF4(bB, 1, 1);
    STAGE_B(0, bS10, bS11, bD10, bD11, t2);
    MFMA16(1, 0, afB, bA);
    DRAIN4;
    BAR;
    // p7: MFMA (0,1) buf1; tail-read afA[0:2] <- A(0,MQ0,t2); stage A(1,h0,t3)
    STAGE_A(1, aS00, aS01, aD00, aD01, t3);
    MFMA16(0, 1, afA, bB);
    READ_AF_H(afA, 0, 0, 0);
    BAR;
    // p8: MFMA (1,1) buf1; read afA[2:4], bA <- buf0 NQ0; stage B(1,h0,t3); drain
    READ_AF_H(afA, 0, 0, 2);
    READ_BF4(bA, 0, 0);
    STAGE_B(1, bS00, bS01, bD00, bD01, t3);
    MFMA16(1, 1, afB, bB);
    DRAIN4;
    BAR;
  }

  // Epilogue: C = acc + bias. acc frag: col = l15, row = (lane>>4)*4 + i.
  const int csub = lane >> 4;
  #pragma unroll
  for (int nf = 0; nf < 4; ++nf) {
    const int col = bn * 256 + wn * 64 + nf * 16 + l15;
    const float bv = bias[col];
    #pragma unroll
    for (int mf = 0; mf < 8; ++mf) {
      const int row = bm * 256 + wm * 128 + mf * 16 + csub * 4;
      #pragma unroll
      for (int i = 0; i < 4; ++i)
        C[(size_t)(row + i) * OUT_F + col] = acc[mf][nf][i] + bv;
    }
  }
}

// ---------------------------------------------------------------------------
extern "C" void kernel_launch(void* const* d_in, const int* in_sizes, int n_in,
                              void* d_out, int out_size, void* d_ws, size_t ws_size,
                              hipStream_t stream) {
  const float* x    = (const float*)d_in[0];
  const int*   qw   = (const int*)d_in[1];
  const float* wsc  = (const float*)d_in[2];
  const float* bias = (const float*)d_in[3];
  const float* pd   = (const float*)d_in[4];
  const float* pu   = (const float*)d_in[5];
  float* out = (float*)d_out;

  ushort* Aext = (ushort*)d_ws;                        // [4096][4224] bf16
  ushort* Bext = Aext + (size_t)NTOK * KTOT;           // [4096][4224] bf16
  ushort* pdT  = Bext + (size_t)OUT_F * KTOT;          // [32][4096] bf16
  float*  part = (float*)(pdT + (size_t)RANK * IN_F);  // [4][4096][32] f32

  hipFuncSetAttribute(reinterpret_cast<const void*>(gemm256_kernel),
                      hipFuncAttributeMaxDynamicSharedMemorySize, 131072);

  quant_kernel <<<16384, 256, 0, stream>>>(x, Aext);
  wdeq_kernel  <<< 8192, 256, 0, stream>>>(qw, wsc, Bext);
  aux_kernel   <<<   16, 256, 0, stream>>>(pd, pu, Bext, pdT);
  lr_kernel    <<<  256, 256, 0, stream>>>(Aext, pdT, part);
  lrcomb_kernel<<<  512, 256, 0, stream>>>(part, Aext);
  gemm256_kernel<<< 256, 512, 131072, stream>>>(Aext, Bext, bias, out);
}

// Round 10
// 176.000 us; speedup vs baseline: 2.1174x; 1.2768x over previous
//
#include <hip/hip_runtime.h>
#include <hip/hip_bf16.h>

#define IN_F  4096
#define OUT_F 4096
#define NTOK  4096
#define RANK  32
#define GS    64
#define NG    64
#define KTOT  4224          // 4096 + 32 (low-rank) + 96 zero pad -> 66 * 64
#define NKT   66
#define ITERS 33
#define KCH   1024

typedef __attribute__((ext_vector_type(4))) float f32x4;
typedef __attribute__((ext_vector_type(8))) short bf16x8;

#define AS1 __attribute__((address_space(1)))
#define AS3 __attribute__((address_space(3)))

__device__ __forceinline__ ushort f2bf(float f) {
  union { float f; uint u; } c; c.f = f;
  const uint u = c.u;
  return (ushort)((u + 0x7fffu + ((u >> 16) & 1u)) >> 16);  // RNE
}

// ---------------------------------------------------------------------------
// Kernel 1 (fused prep): blocks [0,16384) = quant, [16384,24576) = wdeq,
// [24576,24592) = aux (pu^T + zero pad + pdT transpose).
// ---------------------------------------------------------------------------
__global__ __launch_bounds__(256)
void prep_kernel(const float* __restrict__ x, const int* __restrict__ qw,
                 const float* __restrict__ wsc, const float* __restrict__ pd,
                 const float* __restrict__ pu, ushort* __restrict__ Aext,
                 ushort* __restrict__ Bext, ushort* __restrict__ pdT)
{
  const int bid = blockIdx.x;
  if (bid < 16384) {
    // ---- quant: per-group int8 quant+dequant of x -> Aext[:,0:4096] ----
    const int tid  = threadIdx.x;
    const int wave = tid >> 6, lane = tid & 63;
    const int sub  = lane & 15;
    const int ggrp = bid * 16 + wave * 4 + (lane >> 4);
    const int row  = ggrp >> 6, g = ggrp & 63;

    const float4 v = *(const float4*)(x + (size_t)row * IN_F + g * GS + sub * 4);
    float m = fmaxf(fmaxf(fabsf(v.x), fabsf(v.y)), fmaxf(fabsf(v.z), fabsf(v.w)));
    m = fmaxf(m, __shfl_xor(m, 1));
    m = fmaxf(m, __shfl_xor(m, 2));
    m = fmaxf(m, __shfl_xor(m, 4));
    m = fmaxf(m, __shfl_xor(m, 8));
    const float ascale = (m > 0.f) ? m * (1.f / 127.f) : 1.f;

    const float d0 = fminf(fmaxf(rintf(v.x / ascale), -127.f), 127.f) * ascale;
    const float d1 = fminf(fmaxf(rintf(v.y / ascale), -127.f), 127.f) * ascale;
    const float d2 = fminf(fmaxf(rintf(v.z / ascale), -127.f), 127.f) * ascale;
    const float d3 = fminf(fmaxf(rintf(v.w / ascale), -127.f), 127.f) * ascale;

    uint2 st;
    st.x = (uint)f2bf(d0) | ((uint)f2bf(d1) << 16);
    st.y = (uint)f2bf(d2) | ((uint)f2bf(d3) << 16);
    *(uint2*)(Aext + (size_t)row * KTOT + g * GS + sub * 4) = st;
  } else if (bid < 24576) {
    // ---- wdeq: int4 weights -> Bext[:,0:4096] bf16 ----
    const int gidx = (bid - 16384) * 256 + threadIdx.x;
    const int o  = gidx >> 9;
    const int i0 = (gidx & 511) << 3;
    const float sc = wsc[o * NG + (i0 >> 6)];
    const int4 qa = *(const int4*)(qw + (size_t)o * IN_F + i0);
    const int4 qb = *(const int4*)(qw + (size_t)o * IN_F + i0 + 4);
    uint4 st;
    st.x = (uint)f2bf(qa.x * sc) | ((uint)f2bf(qa.y * sc) << 16);
    st.y = (uint)f2bf(qa.z * sc) | ((uint)f2bf(qa.w * sc) << 16);
    st.z = (uint)f2bf(qb.x * sc) | ((uint)f2bf(qb.y * sc) << 16);
    st.w = (uint)f2bf(qb.z * sc) | ((uint)f2bf(qb.w * sc) << 16);
    *(uint4*)(Bext + (size_t)o * KTOT + i0) = st;
  } else {
    // ---- aux: pu^T -> Bext[:,4096:4128], zero 4128:4224; pd -> pdT ----
    const int id = (bid - 24576) * 256 + threadIdx.x;
    ushort* dst = Bext + (size_t)id * KTOT + IN_F;
    #pragma unroll
    for (int r = 0; r < RANK; ++r) {
      dst[r]            = f2bf(pu[(size_t)r * OUT_F + id]);
      dst[RANK + r]     = 0;
      dst[2 * RANK + r] = 0;
      dst[3 * RANK + r] = 0;
    }
    #pragma unroll
    for (int r = 0; r < RANK; ++r)
      pdT[(size_t)r * IN_F + id] = f2bf(pd[(size_t)id * RANK + r]);
  }
}

// ---------------------------------------------------------------------------
// Kernel 2: lr partials = Aq @ pdT^T via MFMA (64 M-tiles x 4 K-chunks).
// ---------------------------------------------------------------------------
__global__ __launch_bounds__(256)
void lr_kernel(const ushort* __restrict__ A, const ushort* __restrict__ pdT,
               float* __restrict__ part)
{
  __shared__ alignas(16) ushort lA[64 * 64];
  const int tid  = threadIdx.x;
  const int wave = tid >> 6, lane = tid & 63;
  const int mt = blockIdx.x >> 2;
  const int kc = blockIdx.x & 3;
  const int k0 = kc * KCH;

  const int tr  = tid >> 3;
  const int scc = (tid & 7) ^ (tr & 7);
  const ushort* aSrc = A + (size_t)(mt * 64 + tr) * KTOT + k0 + scc * 8;
  char* ldsA = (char*)lA + wave * 1024;

  f32x4 acc[2];
  #pragma unroll
  for (int n = 0; n < 2; ++n) acc[n] = f32x4{0.f, 0.f, 0.f, 0.f};

  for (int kt = 0; kt < KCH / 64; ++kt) {
    const ushort* aS = aSrc + kt * 64;
    #pragma unroll
    for (int j = 0; j < 2; ++j)
      __builtin_amdgcn_global_load_lds(
          (const AS1 void*)(aS + (size_t)j * 32 * KTOT),
          (AS3 void*)(ldsA + j * 4096), 16, 0, 0);
    __syncthreads();
    #pragma unroll
    for (int ks = 0; ks < 2; ++ks) {
      const int kb  = (ks * 32 + (lane >> 4) * 8) * 2;
      const int row = wave * 16 + (lane & 15);
      const int addr = (row * 128 + kb) ^ ((row & 7) << 4);
      bf16x8 af = *(const bf16x8*)((const char*)lA + addr);
      #pragma unroll
      for (int n = 0; n < 2; ++n) {
        const int prow = n * 16 + (lane & 15);
        bf16x8 bf = *(const bf16x8*)(pdT + (size_t)prow * IN_F + k0 + kt * 64 + ks * 32 + (lane >> 4) * 8);
        acc[n] = __builtin_amdgcn_mfma_f32_16x16x32_bf16(af, bf, acc[n], 0, 0, 0);
      }
    }
    __syncthreads();
  }
  const int r0   = lane & 15;
  const int rowb = mt * 64 + wave * 16 + (lane >> 4) * 4;
  #pragma unroll
  for (int n = 0; n < 2; ++n)
    #pragma unroll
    for (int i = 0; i < 4; ++i)
      part[((size_t)kc * 4096 + rowb + i) * 32 + n * 16 + r0] = acc[n][i];
}

// ---------------------------------------------------------------------------
// Kernel 3: combine lr partials -> A_ext[:, 4096:4128], zero 4128:4224.
// ---------------------------------------------------------------------------
__global__ __launch_bounds__(256)
void lrcomb_kernel(const float* __restrict__ part, ushort* __restrict__ Aext)
{
  const int id  = blockIdx.x * 256 + threadIdx.x;
  const int row = id >> 5, r = id & 31;
  const float s = part[(size_t)row * 32 + r]
                + part[(size_t)(4096 + row) * 32 + r]
                + part[(size_t)(8192 + row) * 32 + r]
                + part[(size_t)(12288 + row) * 32 + r];
  ushort* dst = Aext + (size_t)row * KTOT + IN_F;
  dst[r]            = f2bf(s);
  dst[RANK + r]     = 0;
  dst[2 * RANK + r] = 0;
  dst[3 * RANK + r] = 0;
}

// ---------------------------------------------------------------------------
// Kernel 4: 256x256 GEMM, R10: R6 schedule with MERGED phase pairs.
// 4 merged phases/iter (half the barriers of R6), same minimal read ledger
// (24 b128/wave/K-tile), same stage schedule (2 stages = 4 loads per phase).
// Merged phase: [reads; 2 stages; BAR; 32 MFMA (setprio); [vmcnt(4)]; BAR].
// Drains at M2/M4 leave exactly the current phase's 4 loads outstanding.
// LDS: A buf b at b*32768 (quarter q at +q*8192), B at 65536+b*32768.
// Swizzle ^((r&7)<<4). Tail stages clamped to tile 65 (zeros).
// Ledger: M1 st A(1,h1,t1),B(1,h1,t1) -> read M3/M4 (drained M2)
//         M2 st A(0,h0,t2),B(0,h0,t2) -> read M1'   (drained M4)
//         M3 st A(0,h1,t2),B(0,h1,t2) -> read M1'/M2' (drained M4)
//         M4 st A(1,h0,t3),B(1,h0,t3) -> read M3'   (drained M2')
// ---------------------------------------------------------------------------
#define READ_AF8(DST, B_, MQ_)                                                   \
  { _Pragma("unroll")                                                            \
    for (int mf = 0; mf < 4; ++mf) {                                             \
      DST[mf][0] = *(const bf16x8*)(lds + afB0 + ((B_) * 32768 + (MQ_) * 8192 + mf * 2048)); \
      DST[mf][1] = *(const bf16x8*)(lds + afB1 + ((B_) * 32768 + (MQ_) * 8192 + mf * 2048)); \
    } }

#define READ_BF4(DST, B_, NQ_)                                                   \
  { _Pragma("unroll")                                                            \
    for (int nf = 0; nf < 2; ++nf) {                                             \
      DST[nf][0] = *(const bf16x8*)(lds + bfB0 + ((B_) * 32768 + (NQ_) * 4096 + nf * 2048)); \
      DST[nf][1] = *(const bf16x8*)(lds + bfB1 + ((B_) * 32768 + (NQ_) * 4096 + nf * 2048)); \
    } }

#define MFMA16(MQ_, NQ_, AF, BF)                                                 \
  _Pragma("unroll")                                                              \
  for (int mf = 0; mf < 4; ++mf)                                                 \
    _Pragma("unroll")                                                            \
    for (int nf = 0; nf < 2; ++nf)                                               \
      _Pragma("unroll")                                                          \
      for (int ks = 0; ks < 2; ++ks)                                             \
        acc[(MQ_) * 4 + mf][(NQ_) * 2 + nf] =                                    \
            __builtin_amdgcn_mfma_f32_16x16x32_bf16(AF[mf][ks], BF[nf][ks],      \
                acc[(MQ_) * 4 + mf][(NQ_) * 2 + nf], 0, 0, 0);

#define STAGE_A(B_, S0, S1, D0, D1, T_)                                          \
  { const ushort* s0 = Atile + S0 + (T_) * 64;                                   \
    const ushort* s1 = Atile + S1 + (T_) * 64;                                   \
    __builtin_amdgcn_global_load_lds((const AS1 void*)s0,                        \
        (AS3 void*)(lds + (B_) * 32768 + D0), 16, 0, 0);                         \
    __builtin_amdgcn_global_load_lds((const AS1 void*)s1,                        \
        (AS3 void*)(lds + (B_) * 32768 + D1), 16, 0, 0); }

#define STAGE_B(B_, S0, S1, D0, D1, T_)                                          \
  { const ushort* s0 = Btile + S0 + (T_) * 64;                                   \
    const ushort* s1 = Btile + S1 + (T_) * 64;                                   \
    __builtin_amdgcn_global_load_lds((const AS1 void*)s0,                        \
        (AS3 void*)(lds + 65536 + (B_) * 32768 + D0), 16, 0, 0);                 \
    __builtin_amdgcn_global_load_lds((const AS1 void*)s1,                        \
        (AS3 void*)(lds + 65536 + (B_) * 32768 + D1), 16, 0, 0); }

#define BAR __builtin_amdgcn_s_barrier()
#define DRAIN4 asm volatile("s_waitcnt vmcnt(4)" ::: "memory")
#define PRIO1 __builtin_amdgcn_s_setprio(1)
#define PRIO0 __builtin_amdgcn_s_setprio(0)

__global__ __launch_bounds__(512, 2)
void gemm256_kernel(const ushort* __restrict__ A, const ushort* __restrict__ B,
                    const float* __restrict__ bias, float* __restrict__ C)
{
  extern __shared__ char lds[];
  const int tid = threadIdx.x;
  const int w = tid >> 6, lane = tid & 63;
  const int l15 = lane & 15;
  const int wm = w >> 2, wn = w & 3;          // 2 x 4 waves

  // ds_read base vaddrs; imm offsets carry B_/MQ_/NQ_/frag (fit 16-bit).
  const int swz0 = (l15 * 128 + (lane >> 4) * 16) ^ ((l15 & 7) << 4);
  const int swz1 = (l15 * 128 + 64 + (lane >> 4) * 16) ^ ((l15 & 7) << 4);
  const int afB0 = wm * 16384 + swz0;
  const int afB1 = wm * 16384 + swz1;
  const int bfB0 = 65536 + wn * 8192 + swz0;
  const int bfB1 = 65536 + wn * 8192 + swz1;

  // Stage source offsets (ushort units) and LDS dest offsets (bytes).
  const int coff = ((lane & 7) ^ (lane >> 3)) << 3;
  const int g0 = w * 2, g1 = w * 2 + 1;
  const int aq0 = (g0 >> 3) * 2, asub0 = g0 & 7;
  const int aq1 = (g1 >> 3) * 2, asub1 = g1 & 7;
  const int aS00 = (aq0 * 64 + asub0 * 8 + (lane >> 3)) * KTOT + coff;
  const int aS01 = (aq1 * 64 + asub1 * 8 + (lane >> 3)) * KTOT + coff;
  const int aS10 = ((aq0 + 1) * 64 + asub0 * 8 + (lane >> 3)) * KTOT + coff;
  const int aS11 = ((aq1 + 1) * 64 + asub1 * 8 + (lane >> 3)) * KTOT + coff;
  const int aD00 = aq0 * 8192 + asub0 * 1024;
  const int aD01 = aq1 * 8192 + asub1 * 1024;
  const int aD10 = (aq0 + 1) * 8192 + asub0 * 1024;
  const int aD11 = (aq1 + 1) * 8192 + asub1 * 1024;
  const int bj0 = g0 >> 2, bsub0 = g0 & 3;
  const int bj1 = g1 >> 2, bsub1 = g1 & 3;
  const int bS00 = (bj0 * 64 + bsub0 * 8 + (lane >> 3)) * KTOT + coff;
  const int bS01 = (bj1 * 64 + bsub1 * 8 + (lane >> 3)) * KTOT + coff;
  const int bS10 = (bj0 * 64 + 32 + bsub0 * 8 + (lane >> 3)) * KTOT + coff;
  const int bS11 = (bj1 * 64 + 32 + bsub1 * 8 + (lane >> 3)) * KTOT + coff;
  const int bD00 = bj0 * 8192 + bsub0 * 1024;
  const int bD01 = bj1 * 8192 + bsub1 * 1024;
  const int bD10 = bj0 * 8192 + 4096 + bsub0 * 1024;
  const int bD11 = bj1 * 8192 + 4096 + bsub1 * 1024;

  // 2-D XCD chunk swizzle: each XCD owns a 4x8 (bm x bn) region.
  const int xcd = blockIdx.x & 7, idx = blockIdx.x >> 3;
  const int bm = (xcd >> 1) * 4 + (idx >> 3);
  const int bn = (xcd & 1) * 8 + (idx & 7);

  const ushort* Atile = A + (size_t)bm * 256 * KTOT;
  const ushort* Btile = B + (size_t)bn * 256 * KTOT;

  f32x4 acc[8][4];
  #pragma unroll
  for (int m = 0; m < 8; ++m)
    #pragma unroll
    for (int n = 0; n < 4; ++n)
      acc[m][n] = f32x4{0.f, 0.f, 0.f, 0.f};

  bf16x8 afA[4][2], af2[4][2], b0[2][2], b1[2][2];

  // Prologue: buf0 <- tile 0 full (8 loads); buf1 <- tile 1 h0 (4 loads).
  STAGE_A(0, aS00, aS01, aD00, aD01, 0);
  STAGE_B(0, bS00, bS01, bD00, bD01, 0);
  STAGE_A(0, aS10, aS11, aD10, aD11, 0);
  STAGE_B(0, bS10, bS11, bD10, bD11, 0);
  STAGE_A(1, aS00, aS01, aD00, aD01, 1);
  STAGE_B(1, bS00, bS01, bD00, bD01, 1);
  DRAIN4;           // buf0 complete; buf1-h0's 4 loads outstanding
  BAR;

  #pragma unroll 1
  for (int j = 0; j < ITERS; ++j) {
    const int t1 = 2 * j + 1;
    const int t2 = (2 * j + 2 < NKT) ? 2 * j + 2 : NKT - 1;   // clamped
    const int t3 = (2 * j + 3 < NKT) ? 2 * j + 3 : NKT - 1;   // (tile 65 = 0)

    // M1: reads buf0 {afA(MQ0), b0, b1}; stage A(1,h1,t1)+B(1,h1,t1);
    //     MFMA (0,0)+(0,1) buf0.
    READ_AF8(afA, 0, 0);
    READ_BF4(b0, 0, 0);
    READ_BF4(b1, 0, 1);
    STAGE_A(1, aS10, aS11, aD10, aD11, t1);
    STAGE_B(1, bS10, bS11, bD10, bD11, t1);
    BAR;
    PRIO1; MFMA16(0, 0, afA, b0); MFMA16(0, 1, afA, b1); PRIO0;
    BAR;
    // M2: reads buf0 {af2(MQ1)}; stage A(0,h0,t2)+B(0,h0,t2);
    //     MFMA (1,0)+(1,1) buf0; drain.
    READ_AF8(af2, 0, 1);
    STAGE_A(0, aS00, aS01, aD00, aD01, t2);
    STAGE_B(0, bS00, bS01, bD00, bD01, t2);
    BAR;
    PRIO1; MFMA16(1, 0, af2, b0); MFMA16(1, 1, af2, b1); PRIO0;
    DRAIN4;
    BAR;
    // M3: reads buf1 {afA(MQ0), b0, b1}; stage A(0,h1,t2)+B(0,h1,t2);
    //     MFMA (0,0)+(0,1) buf1.
    READ_AF8(afA, 1, 0);
    READ_BF4(b0, 1, 0);
    READ_BF4(b1, 1, 1);
    STAGE_A(0, aS10, aS11, aD10, aD11, t2);
    STAGE_B(0, bS10, bS11, bD10, bD11, t2);
    BAR;
    PRIO1; MFMA16(0, 0, afA, b0); MFMA16(0, 1, afA, b1); PRIO0;
    BAR;
    // M4: reads buf1 {af2(MQ1)}; stage A(1,h0,t3)+B(1,h0,t3);
    //     MFMA (1,0)+(1,1) buf1; drain.
    READ_AF8(af2, 1, 1);
    STAGE_A(1, aS00, aS01, aD00, aD01, t3);
    STAGE_B(1, bS00, bS01, bD00, bD01, t3);
    BAR;
    PRIO1; MFMA16(1, 0, af2, b0); MFMA16(1, 1, af2, b1); PRIO0;
    DRAIN4;
    BAR;
  }

  // Epilogue: C = acc + bias. acc frag: col = l15, row = (lane>>4)*4 + i.
  const int csub = lane >> 4;
  #pragma unroll
  for (int nf = 0; nf < 4; ++nf) {
    const int col = bn * 256 + wn * 64 + nf * 16 + l15;
    const float bv = bias[col];
    #pragma unroll
    for (int mf = 0; mf < 8; ++mf) {
      const int row = bm * 256 + wm * 128 + mf * 16 + csub * 4;
      #pragma unroll
      for (int i = 0; i < 4; ++i)
        C[(size_t)(row + i) * OUT_F + col] = acc[mf][nf][i] + bv;
    }
  }
}

// ---------------------------------------------------------------------------
extern "C" void kernel_launch(void* const* d_in, const int* in_sizes, int n_in,
                              void* d_out, int out_size, void* d_ws, size_t ws_size,
                              hipStream_t stream) {
  const float* x    = (const float*)d_in[0];
  const int*   qw   = (const int*)d_in[1];
  const float* wsc  = (const float*)d_in[2];
  const float* bias = (const float*)d_in[3];
  const float* pd   = (const float*)d_in[4];
  const float* pu   = (const float*)d_in[5];
  float* out = (float*)d_out;

  ushort* Aext = (ushort*)d_ws;                        // [4096][4224] bf16
  ushort* Bext = Aext + (size_t)NTOK * KTOT;           // [4096][4224] bf16
  ushort* pdT  = Bext + (size_t)OUT_F * KTOT;          // [32][4096] bf16
  float*  part = (float*)(pdT + (size_t)RANK * IN_F);  // [4][4096][32] f32

  hipFuncSetAttribute(reinterpret_cast<const void*>(gemm256_kernel),
                      hipFuncAttributeMaxDynamicSharedMemorySize, 131072);

  prep_kernel  <<<24592, 256, 0, stream>>>(x, qw, wsc, pd, pu, Aext, Bext, pdT);
  lr_kernel    <<<  256, 256, 0, stream>>>(Aext, pdT, part);
  lrcomb_kernel<<<  512, 256, 0, stream>>>(part, Aext);
  gemm256_kernel<<< 256, 512, 131072, stream>>>(Aext, Bext, bias, out);
}